// Round 1
// baseline (2997.908 us; speedup 1.0000x reference)
//
#include <hip/hip_runtime.h>
#include <stdint.h>
#include <stddef.h>

// Problem constants
#define TB    4096   // sequence length T
#define NDIM  1024   // model dim
#define NH    16     // heads
#define KPROJ 256    // linformer k
#define DH    64     // dim head
#define NBH   64     // B * NH
#define NB    4      // batch

typedef _Float16 f16;
typedef _Float16 half2_t __attribute__((ext_vector_type(2)));

__device__ __forceinline__ float fdot2f(uint32_t a, uint32_t b, float c) {
#if __has_builtin(__builtin_amdgcn_fdot2)
  return __builtin_amdgcn_fdot2(__builtin_bit_cast(half2_t, a),
                                __builtin_bit_cast(half2_t, b), c, false);
#else
  half2_t ha = __builtin_bit_cast(half2_t, a);
  half2_t hb = __builtin_bit_cast(half2_t, b);
  return c + (float)ha.x * (float)hb.x + (float)ha.y * (float)hb.y;
#endif
}

// ---------------------------------------------------------------------------
// Stage 1: qkv = x @ Wqkv   (M=16384, N=3072, K=1024), fp32 VALU, 128x128x16
// tiles, 8x8 microtile. Epilogue scatters to q/k/v [bh][t][d] fp16 buffers
// using the einops split f = 48*d + 16*r + h  (r: 0=q,1=k,2=v).
// ---------------------------------------------------------------------------
__launch_bounds__(256)
__global__ void k_qkv(const float* __restrict__ X, const float* __restrict__ W,
                      f16* __restrict__ qb, f16* __restrict__ kb, f16* __restrict__ vb) {
  __shared__ float As[16][132];  // [k][m], padded
  __shared__ float Bs[16][132];  // [k][n], padded
  const int tid = threadIdx.x;
  const int bn0 = blockIdx.x * 128;
  const int bm0 = blockIdx.y * 128;
  const int tx = tid & 15, ty = tid >> 4;
  float acc[8][8];
#pragma unroll
  for (int i = 0; i < 8; ++i)
#pragma unroll
    for (int j = 0; j < 8; ++j) acc[i][j] = 0.f;

  for (int k0 = 0; k0 < NDIM; k0 += 16) {
    // A tile 128x16 (transpose into LDS)
#pragma unroll
    for (int rep = 0; rep < 2; ++rep) {
      int idx = rep * 1024 + tid * 4;
      int r = idx >> 4, c = idx & 15;
      const float4 a = *(const float4*)&X[(size_t)(bm0 + r) * NDIM + k0 + c];
      As[c + 0][r] = a.x; As[c + 1][r] = a.y; As[c + 2][r] = a.z; As[c + 3][r] = a.w;
    }
    // B tile 16x128
#pragma unroll
    for (int rep = 0; rep < 2; ++rep) {
      int idx = rep * 1024 + tid * 4;
      int r = idx >> 7, c = idx & 127;
      *(float4*)&Bs[r][c] = *(const float4*)&W[(size_t)(k0 + r) * (3 * NDIM) + bn0 + c];
    }
    __syncthreads();
#pragma unroll
    for (int kk = 0; kk < 16; ++kk) {
      float a[8], b[8];
      *(float4*)&a[0] = *(const float4*)&As[kk][ty * 8];
      *(float4*)&a[4] = *(const float4*)&As[kk][ty * 8 + 4];
      *(float4*)&b[0] = *(const float4*)&Bs[kk][tx * 8];
      *(float4*)&b[4] = *(const float4*)&Bs[kk][tx * 8 + 4];
#pragma unroll
      for (int i = 0; i < 8; ++i)
#pragma unroll
        for (int j = 0; j < 8; ++j) acc[i][j] = fmaf(a[i], b[j], acc[i][j]);
    }
    __syncthreads();
  }
  // scatter epilogue
#pragma unroll
  for (int i = 0; i < 8; ++i) {
    int m = bm0 + ty * 8 + i;
    int b = m >> 12, t = m & 4095;
#pragma unroll
    for (int j = 0; j < 8; ++j) {
      int f = bn0 + tx * 8 + j;
      int d = f / 48;
      int rem = f - d * 48;
      int rr = rem >> 4, h = rem & 15;
      f16* dst = (rr == 0) ? qb : (rr == 1) ? kb : vb;
      dst[(size_t)((b * NH + h) * TB + t) * DH + d] = (f16)acc[i][j];
    }
  }
}

// ---------------------------------------------------------------------------
// Stage 2: kp/vp partials: part[seg][r][bh][kap][d] = sum_{t in seg} P[t][kap]*kv[r][bh][t][d]
// grid (4 seg, 64 bh, 2 r); thread = kappa (256), acc[64] in regs, fp32.
// ---------------------------------------------------------------------------
__launch_bounds__(256)
__global__ void k_proj(const f16* __restrict__ kv, const float* __restrict__ P,
                       float* __restrict__ part) {
  __shared__ float in_s[64][64];
  const int tid = threadIdx.x;
  const int seg = blockIdx.x, bh = blockIdx.y, r = blockIdx.z;
  const f16* in = kv + ((size_t)r * NBH + bh) * (size_t)TB * DH;
  const int kap = tid;
  float acc[64];
#pragma unroll
  for (int d = 0; d < 64; ++d) acc[d] = 0.f;

  for (int chunk = 0; chunk < 16; ++chunk) {
    const int t0 = seg * 1024 + chunk * 64;
    {
      int tl = tid >> 2, d0 = (tid & 3) * 16;
      const f16* src = in + (size_t)(t0 + tl) * DH + d0;
#pragma unroll
      for (int v = 0; v < 16; v += 8) {
        uint4 u = *(const uint4*)(src + v);
        const f16* hp = (const f16*)&u;
#pragma unroll
        for (int e = 0; e < 8; ++e) in_s[tl][d0 + v + e] = (float)hp[e];
      }
    }
    __syncthreads();
#pragma unroll 4
    for (int tt = 0; tt < 64; ++tt) {
      float p = P[(size_t)(t0 + tt) * KPROJ + kap];
#pragma unroll
      for (int d4 = 0; d4 < 64; d4 += 4) {
        float4 iv = *(const float4*)&in_s[tt][d4];
        acc[d4 + 0] = fmaf(p, iv.x, acc[d4 + 0]);
        acc[d4 + 1] = fmaf(p, iv.y, acc[d4 + 1]);
        acc[d4 + 2] = fmaf(p, iv.z, acc[d4 + 2]);
        acc[d4 + 3] = fmaf(p, iv.w, acc[d4 + 3]);
      }
    }
    __syncthreads();
  }
  float* dst = part + (((size_t)seg * 2 + r) * NBH + bh) * (KPROJ * DH) + (size_t)kap * DH;
#pragma unroll
  for (int d4 = 0; d4 < 64; d4 += 4) {
    float4 v; v.x = acc[d4]; v.y = acc[d4 + 1]; v.z = acc[d4 + 2]; v.w = acc[d4 + 3];
    *(float4*)&dst[d4] = v;
  }
}

// Reduce 4 seg partials -> kpv fp16 [r][bh][j][d]  (4 MB)
__launch_bounds__(256)
__global__ void k_reduce(const float* __restrict__ part, f16* __restrict__ kpv) {
  size_t i = (size_t)blockIdx.x * 256 + threadIdx.x;  // 0 .. 2M-1
  float v = 0.f;
#pragma unroll
  for (int seg = 0; seg < 4; ++seg) v += part[(size_t)seg * (2u * NBH * KPROJ * DH) + i];
  kpv[i] = (f16)v;
}

// ---------------------------------------------------------------------------
// Stage 3+4: fused attention. grid (128 row-tiles, 64 bh), 256 thr = 4 waves,
// 32 rows/wg. LDS: kp_s [j][d-pair] and vp_t [d][j-pair], both fp16 XOR-
// swizzled for conflict-free access. Softmax in fp32, dot products via fdot2.
// ---------------------------------------------------------------------------
__launch_bounds__(256)
__global__ void k_attn(const f16* __restrict__ qb, const f16* __restrict__ kpv,
                       f16* __restrict__ aout) {
  __shared__ uint32_t kp_s[KPROJ * 32];  // 32 KB
  __shared__ uint32_t vp_t[DH * 128];    // 32 KB
  const int tid = threadIdx.x;
  const int bh = blockIdx.y;
  const int row0 = blockIdx.x * 32;

  {  // loader: 16384 elems each of kp and vp
    const uint16_t* kp_g = (const uint16_t*)(kpv + (size_t)bh * (KPROJ * DH));
    const uint16_t* vp_g = (const uint16_t*)(kpv + ((size_t)NBH + bh) * (KPROJ * DH));
    uint16_t* kp16 = (uint16_t*)kp_s;
    uint16_t* vp16 = (uint16_t*)vp_t;
#pragma unroll 4
    for (int rep = 0; rep < 64; ++rep) {
      int idx = rep * 256 + tid;
      int j = idx >> 6, d = idx & 63;
      uint16_t hk = kp_g[idx];
      uint16_t hv = vp_g[idx];
      kp16[(j * 32 + ((d >> 1) ^ (j & 31))) * 2 + (d & 1)] = hk;
      vp16[(d * 128 + ((j >> 1) ^ (d & 31))) * 2 + (j & 1)] = hv;
    }
  }
  __syncthreads();

  const int wid = tid >> 6, lane = tid & 63;
  const int b = bh >> 4, h = bh & 15;
  for (int rr = 0; rr < 8; ++rr) {
    const int row = row0 + wid * 8 + rr;
    const uint32_t* qp = (const uint32_t*)(qb + ((size_t)bh * TB + row) * DH);
    uint32_t qw = (lane < 32) ? qp[lane] : 0u;
    float s[4] = {0.f, 0.f, 0.f, 0.f};
#pragma unroll 8
    for (int p = 0; p < 32; ++p) {
      uint32_t uq = (uint32_t)__shfl((int)qw, p);
#pragma unroll
      for (int i = 0; i < 4; ++i) {
        int j = i * 64 + lane;
        uint32_t ukp = kp_s[j * 32 + (p ^ (j & 31))];
        s[i] = fdot2f(ukp, uq, s[i]);
      }
    }
    float m = -1e30f;
#pragma unroll
    for (int i = 0; i < 4; ++i) { s[i] *= 0.125f; m = fmaxf(m, s[i]); }
#pragma unroll
    for (int off = 32; off > 0; off >>= 1) m = fmaxf(m, __shfl_xor(m, off));
    float e[4], sum = 0.f;
#pragma unroll
    for (int i = 0; i < 4; ++i) { e[i] = __expf(s[i] - m); sum += e[i]; }
#pragma unroll
    for (int off = 32; off > 0; off >>= 1) sum += __shfl_xor(sum, off);
    // pack (e_j, e_{j+1}) as half2 on even lanes
    uint32_t pk[4];
#pragma unroll
    for (int i = 0; i < 4; ++i) {
      f16 hh = (f16)e[i];
      uint32_t hb = (uint32_t)__builtin_bit_cast(uint16_t, hh);
      uint32_t nb = (uint32_t)__shfl_xor((int)hb, 1);
      pk[i] = (hb & 0xffffu) | (nb << 16);
    }
    float acc = 0.f;
#pragma unroll 4
    for (int p = 0; p < 32; ++p) {
#pragma unroll
      for (int i = 0; i < 4; ++i) {
        uint32_t pe = (uint32_t)__shfl((int)pk[i], 2 * p);
        uint32_t uv = vp_t[lane * 128 + ((i * 32 + p) ^ (lane & 31))];
        acc = fdot2f(uv, pe, acc);
      }
    }
    aout[((size_t)(b * TB + row)) * NDIM + h * DH + lane] = (f16)(acc / sum);
  }
}

// ---------------------------------------------------------------------------
// Stage 5: Out = aout @ W0  (M=16384, N=1024, K=1024), same tiling as k_qkv.
// ---------------------------------------------------------------------------
__launch_bounds__(256)
__global__ void k_out(const f16* __restrict__ A, const float* __restrict__ W,
                      float* __restrict__ Out) {
  __shared__ float As[16][132];
  __shared__ float Bs[16][132];
  const int tid = threadIdx.x;
  const int bn0 = blockIdx.x * 128;
  const int bm0 = blockIdx.y * 128;
  const int tx = tid & 15, ty = tid >> 4;
  float acc[8][8];
#pragma unroll
  for (int i = 0; i < 8; ++i)
#pragma unroll
    for (int j = 0; j < 8; ++j) acc[i][j] = 0.f;

  for (int k0 = 0; k0 < NDIM; k0 += 16) {
    {  // A tile 128x16 halves -> fp32 transposed
      int r = tid >> 1, c = (tid & 1) * 8;
      uint4 u = *(const uint4*)&A[(size_t)(bm0 + r) * NDIM + k0 + c];
      const f16* hp = (const f16*)&u;
#pragma unroll
      for (int e = 0; e < 8; ++e) As[c + e][r] = (float)hp[e];
    }
#pragma unroll
    for (int rep = 0; rep < 2; ++rep) {
      int idx = rep * 1024 + tid * 4;
      int r = idx >> 7, c = idx & 127;
      *(float4*)&Bs[r][c] = *(const float4*)&W[(size_t)(k0 + r) * NDIM + bn0 + c];
    }
    __syncthreads();
#pragma unroll
    for (int kk = 0; kk < 16; ++kk) {
      float a[8], bb[8];
      *(float4*)&a[0] = *(const float4*)&As[kk][ty * 8];
      *(float4*)&a[4] = *(const float4*)&As[kk][ty * 8 + 4];
      *(float4*)&bb[0] = *(const float4*)&Bs[kk][tx * 8];
      *(float4*)&bb[4] = *(const float4*)&Bs[kk][tx * 8 + 4];
#pragma unroll
      for (int i = 0; i < 8; ++i)
#pragma unroll
        for (int j = 0; j < 8; ++j) acc[i][j] = fmaf(a[i], bb[j], acc[i][j]);
    }
    __syncthreads();
  }
#pragma unroll
  for (int i = 0; i < 8; ++i) {
    int m = bm0 + ty * 8 + i;
#pragma unroll
    for (int j = 0; j < 8; j += 4) {
      float4 v;
      v.x = acc[i][j]; v.y = acc[i][j + 1]; v.z = acc[i][j + 2]; v.w = acc[i][j + 3];
      *(float4*)&Out[(size_t)m * NDIM + bn0 + tx * 8 + j] = v;
    }
  }
}

// ---------------------------------------------------------------------------
extern "C" void kernel_launch(void* const* d_in, const int* in_sizes, int n_in,
                              void* d_out, int out_size, void* d_ws, size_t ws_size,
                              hipStream_t stream) {
  const float* X    = (const float*)d_in[0];  // [4,4096,1024]
  const float* P    = (const float*)d_in[1];  // [4096,256]
  const float* Wqkv = (const float*)d_in[2];  // [1024,3072]
  const float* W0   = (const float*)d_in[3];  // [1024,1024]
  float* Out = (float*)d_out;

  char* ws = (char*)d_ws;
  const size_t MB = 1u << 20;
  f16*   qb   = (f16*)(ws);              // 32 MB  [bh][t][d]
  f16*   kb   = (f16*)(ws + 32 * MB);    // 32 MB  (k,v contiguous for k_proj)
  f16*   vb   = (f16*)(ws + 64 * MB);    // 32 MB
  float* part = (float*)(ws + 96 * MB);  // 32 MB  [seg][r][bh][kap][d] fp32
  f16*   kpv  = (f16*)(ws + 128 * MB);   // 4 MB   [r][bh][j][d] fp16
  f16*   aout = (f16*)(ws + 132 * MB);   // 32 MB  [b][t][h*64+d] fp16
  // total 164 MB of workspace

  k_qkv<<<dim3(24, 128), 256, 0, stream>>>(X, Wqkv, qb, kb, vb);
  k_proj<<<dim3(4, 64, 2), 256, 0, stream>>>(kb, P, part);
  k_reduce<<<dim3(8192), 256, 0, stream>>>(part, kpv);
  k_attn<<<dim3(128, 64), 256, 0, stream>>>(qb, kpv, aout);
  k_out<<<dim3(8, 128), 256, 0, stream>>>(aout, W0, Out);
}

// Round 2
// 1166.480 us; speedup vs baseline: 2.5700x; 2.5700x over previous
//
#include <hip/hip_runtime.h>
#include <stdint.h>
#include <stddef.h>

#define TB    4096
#define NDIM  1024
#define NH    16
#define KPROJ 256
#define DH    64
#define NBH   64

typedef _Float16 f16;
typedef _Float16 f16x8 __attribute__((ext_vector_type(8)));
typedef _Float16 half2_t __attribute__((ext_vector_type(2)));
typedef float    f32x4 __attribute__((ext_vector_type(4)));

__device__ __forceinline__ void glds16(const f16* g, f16* l) {
  __builtin_amdgcn_global_load_lds((const __attribute__((address_space(1))) void*)g,
                                   (__attribute__((address_space(3))) void*)l, 16, 0, 0);
}

__device__ __forceinline__ float fdot2f(uint32_t a, uint32_t b, float c) {
#if __has_builtin(__builtin_amdgcn_fdot2)
  return __builtin_amdgcn_fdot2(__builtin_bit_cast(half2_t, a),
                                __builtin_bit_cast(half2_t, b), c, false);
#else
  half2_t ha = __builtin_bit_cast(half2_t, a);
  half2_t hb = __builtin_bit_cast(half2_t, b);
  return c + (float)ha.x * (float)hb.x + (float)ha.y * (float)hb.y;
#endif
}

// ---------------------------------------------------------------------------
// fp32 -> fp16 elementwise (X)
// ---------------------------------------------------------------------------
__launch_bounds__(256)
__global__ void cvt_x(const float* __restrict__ in, f16* __restrict__ out) {
  size_t i = ((size_t)blockIdx.x * 256 + threadIdx.x) * 8;
  float4 v0 = *(const float4*)(in + i);
  float4 v1 = *(const float4*)(in + i + 4);
  union { f16 h[8]; uint4 u; } pk;
  pk.h[0] = (f16)v0.x; pk.h[1] = (f16)v0.y; pk.h[2] = (f16)v0.z; pk.h[3] = (f16)v0.w;
  pk.h[4] = (f16)v1.x; pk.h[5] = (f16)v1.y; pk.h[6] = (f16)v1.z; pk.h[7] = (f16)v1.w;
  *(uint4*)(out + i) = pk.u;
}

// ---------------------------------------------------------------------------
// fp32 [R][C] -> fp16 transposed [C][R]
// ---------------------------------------------------------------------------
__launch_bounds__(256)
__global__ void cvt_t(const float* __restrict__ in, f16* __restrict__ out, int R, int C) {
  __shared__ __align__(16) f16 s[64][72];
  const int tid = threadIdx.x;
  const int c0 = blockIdx.x * 64, r0 = blockIdx.y * 64;
#pragma unroll
  for (int it = 0; it < 4; ++it) {
    int chunk = it * 256 + tid;
    int r_l = chunk >> 4, c4 = (chunk & 15) * 4;
    float4 v = *(const float4*)(in + (size_t)(r0 + r_l) * C + c0 + c4);
    s[c4 + 0][r_l] = (f16)v.x; s[c4 + 1][r_l] = (f16)v.y;
    s[c4 + 2][r_l] = (f16)v.z; s[c4 + 3][r_l] = (f16)v.w;
  }
  __syncthreads();
#pragma unroll
  for (int it = 0; it < 2; ++it) {
    int chunk = it * 256 + tid;
    int c_l = chunk >> 3, rc = (chunk & 7) * 8;
    *(uint4*)(out + (size_t)(c0 + c_l) * R + r0 + rc) = *(const uint4*)&s[c_l][rc];
  }
}

// ---------------------------------------------------------------------------
// Stage 1: qkv = Xh @ Wt^T  (M=16384, N=3072, K=1024) fp16 MFMA, 128x128x32.
// Epilogue: einops split f = 48d+16r+h, store q/k/v TRANSPOSED [bh][d][t]
// (4 consecutive C-rows = 4 consecutive t -> one 8B store; L2 merges lines).
// ---------------------------------------------------------------------------
__launch_bounds__(256)
__global__ void k_qkv(const f16* __restrict__ Xh, const f16* __restrict__ Wt,
                      f16* __restrict__ qt, f16* __restrict__ kvt) {
  __shared__ __align__(16) f16 As[128 * 32];
  __shared__ __align__(16) f16 Bs[128 * 32];
  const int tid = threadIdx.x;
  const int w = tid >> 6, lane = tid & 63;
  const int quad = lane >> 4, l15 = lane & 15;
  const int bn0 = blockIdx.x * 128, bm0 = blockIdx.y * 128;
  const int wm = (w & 1) * 64, wn = (w >> 1) * 64;
  const int srow = lane >> 2, skc = lane & 3;

  f32x4 acc[4][4];
#pragma unroll
  for (int i = 0; i < 4; ++i)
#pragma unroll
    for (int j = 0; j < 4; ++j) acc[i][j] = (f32x4){0.f, 0.f, 0.f, 0.f};

  const f16* Ag0 = Xh + (size_t)(bm0 + w * 32 + srow) * NDIM + skc * 8;
  const f16* Bg0 = Wt + (size_t)(bn0 + w * 32 + srow) * NDIM + skc * 8;
  f16* Al0 = As + (w * 32) * 32;
  f16* Bl0 = Bs + (w * 32) * 32;

  for (int k0 = 0; k0 < NDIM; k0 += 32) {
    glds16(Ag0 + k0, Al0);
    glds16(Ag0 + (size_t)16 * NDIM + k0, Al0 + 16 * 32);
    glds16(Bg0 + k0, Bl0);
    glds16(Bg0 + (size_t)16 * NDIM + k0, Bl0 + 16 * 32);
    __syncthreads();
    f16x8 a[4], b[4];
#pragma unroll
    for (int i = 0; i < 4; ++i) a[i] = *(const f16x8*)(As + (wm + i * 16 + l15) * 32 + quad * 8);
#pragma unroll
    for (int j = 0; j < 4; ++j) b[j] = *(const f16x8*)(Bs + (wn + j * 16 + l15) * 32 + quad * 8);
#pragma unroll
    for (int i = 0; i < 4; ++i)
#pragma unroll
      for (int j = 0; j < 4; ++j)
        acc[i][j] = __builtin_amdgcn_mfma_f32_16x16x32_f16(a[i], b[j], acc[i][j], 0, 0, 0);
    __syncthreads();
  }

#pragma unroll
  for (int i = 0; i < 4; ++i) {
    int mrow = bm0 + wm + i * 16 + quad * 4;
    int bb = mrow >> 12, t = mrow & 4095;
#pragma unroll
    for (int j = 0; j < 4; ++j) {
      int f = bn0 + wn + j * 16 + l15;
      int d = f / 48;
      int rem = f - d * 48;
      int rr = rem >> 4, h = rem & 15;
      f16* base = (rr == 0) ? qt : kvt + (size_t)(rr - 1) * ((size_t)NBH * DH * TB);
      size_t off = ((size_t)((bb * NH + h) * DH + d)) * TB + t;
      union { f16 hh[4]; uint2 u; } pk;
#pragma unroll
      for (int r = 0; r < 4; ++r) pk.hh[r] = (f16)acc[i][j][r];
      *(uint2*)(base + off) = pk.u;
    }
  }
}

// ---------------------------------------------------------------------------
// Stage 2: kp/vp = Pt @ kvt^T per (bh, r): M=128(kappa-split), N=64(d), K=4096(t)
// grid (2 kappa-blocks, 64 bh, 2 r). Output kpv [r][bh][kappa][d] fp16.
// ---------------------------------------------------------------------------
__launch_bounds__(256)
__global__ void k_proj(const f16* __restrict__ Pt, const f16* __restrict__ kvt,
                       f16* __restrict__ kpv) {
  __shared__ __align__(16) f16 As[128 * 32];
  __shared__ __align__(16) f16 Bs[64 * 32];
  const int tid = threadIdx.x;
  const int w = tid >> 6, lane = tid & 63;
  const int quad = lane >> 4, l15 = lane & 15;
  const int km0 = blockIdx.x * 128;
  const int bh = blockIdx.y, rv = blockIdx.z;
  const int srow = lane >> 2, skc = lane & 3;
  const f16* Bbase = kvt + (size_t)(rv * NBH + bh) * DH * TB;  // [d][t]

  f32x4 acc[2][4];
#pragma unroll
  for (int i = 0; i < 2; ++i)
#pragma unroll
    for (int j = 0; j < 4; ++j) acc[i][j] = (f32x4){0.f, 0.f, 0.f, 0.f};

  const f16* Ag0 = Pt + (size_t)(km0 + w * 32 + srow) * TB + skc * 8;
  const f16* Bg0 = Bbase + (size_t)(w * 16 + srow) * TB + skc * 8;
  f16* Al0 = As + (w * 32) * 32;
  f16* Bl0 = Bs + (w * 16) * 32;

  for (int k0 = 0; k0 < TB; k0 += 32) {
    glds16(Ag0 + k0, Al0);
    glds16(Ag0 + (size_t)16 * TB + k0, Al0 + 16 * 32);
    glds16(Bg0 + k0, Bl0);
    __syncthreads();
    f16x8 a[2], b[4];
#pragma unroll
    for (int i = 0; i < 2; ++i) a[i] = *(const f16x8*)(As + (w * 32 + i * 16 + l15) * 32 + quad * 8);
#pragma unroll
    for (int j = 0; j < 4; ++j) b[j] = *(const f16x8*)(Bs + (j * 16 + l15) * 32 + quad * 8);
#pragma unroll
    for (int i = 0; i < 2; ++i)
#pragma unroll
      for (int j = 0; j < 4; ++j)
        acc[i][j] = __builtin_amdgcn_mfma_f32_16x16x32_f16(a[i], b[j], acc[i][j], 0, 0, 0);
    __syncthreads();
  }

#pragma unroll
  for (int i = 0; i < 2; ++i) {
    int kap0 = km0 + w * 32 + i * 16 + quad * 4;
#pragma unroll
    for (int j = 0; j < 4; ++j) {
      int d = j * 16 + l15;
#pragma unroll
      for (int r = 0; r < 4; ++r)
        kpv[((size_t)(rv * NBH + bh) * KPROJ + kap0 + r) * DH + d] = (f16)acc[i][j][r];
    }
  }
}

// ---------------------------------------------------------------------------
// Stage 3+4: fused attention (VALU fdot2, unchanged except q now [bh][d][t]
// -> small LDS transpose of the 32-row q slice).
// ---------------------------------------------------------------------------
__launch_bounds__(256)
__global__ void k_attn(const f16* __restrict__ qt, const f16* __restrict__ kpv,
                       f16* __restrict__ aout) {
  __shared__ uint32_t kp_s[KPROJ * 32];  // 32 KB
  __shared__ uint32_t vp_t[DH * 128];    // 32 KB
  __shared__ __align__(16) uint32_t q_s[32 * 32];  // 4 KB: [t_local][d] as u32 pairs
  const int tid = threadIdx.x;
  const int bh = blockIdx.y;
  const int row0 = blockIdx.x * 32;

  {  // q slice transpose: qt[bh][d][row0..row0+32) -> q_s[t][d]
    int d = tid >> 2, ck = tid & 3;
    uint4 u = *(const uint4*)(qt + ((size_t)(bh * DH + d)) * TB + row0 + ck * 8);
    const f16* hp = (const f16*)&u;
    f16* q16 = (f16*)q_s;
#pragma unroll
    for (int e = 0; e < 8; ++e) q16[(ck * 8 + e) * 64 + d] = hp[e];
  }
  {  // kp/vp loaders with XOR swizzle
    const uint16_t* kp_g = (const uint16_t*)(kpv + (size_t)bh * (KPROJ * DH));
    const uint16_t* vp_g = (const uint16_t*)(kpv + ((size_t)NBH + bh) * (KPROJ * DH));
    uint16_t* kp16 = (uint16_t*)kp_s;
    uint16_t* vp16 = (uint16_t*)vp_t;
#pragma unroll 4
    for (int rep = 0; rep < 64; ++rep) {
      int idx = rep * 256 + tid;
      int j = idx >> 6, d = idx & 63;
      uint16_t hk = kp_g[idx];
      uint16_t hv = vp_g[idx];
      kp16[(j * 32 + ((d >> 1) ^ (j & 31))) * 2 + (d & 1)] = hk;
      vp16[(d * 128 + ((j >> 1) ^ (d & 31))) * 2 + (j & 1)] = hv;
    }
  }
  __syncthreads();

  const int wid = tid >> 6, lane = tid & 63;
  const int b = bh >> 4, h = bh & 15;
  for (int rr = 0; rr < 8; ++rr) {
    const int rloc = wid * 8 + rr;
    const int row = row0 + rloc;
    uint32_t qw = (lane < 32) ? q_s[rloc * 32 + lane] : 0u;
    float s[4] = {0.f, 0.f, 0.f, 0.f};
#pragma unroll 8
    for (int p = 0; p < 32; ++p) {
      uint32_t uq = (uint32_t)__shfl((int)qw, p);
#pragma unroll
      for (int i = 0; i < 4; ++i) {
        int j = i * 64 + lane;
        uint32_t ukp = kp_s[j * 32 + (p ^ (j & 31))];
        s[i] = fdot2f(ukp, uq, s[i]);
      }
    }
    float m = -1e30f;
#pragma unroll
    for (int i = 0; i < 4; ++i) { s[i] *= 0.125f; m = fmaxf(m, s[i]); }
#pragma unroll
    for (int off = 32; off > 0; off >>= 1) m = fmaxf(m, __shfl_xor(m, off));
    float e[4], sum = 0.f;
#pragma unroll
    for (int i = 0; i < 4; ++i) { e[i] = __expf(s[i] - m); sum += e[i]; }
#pragma unroll
    for (int off = 32; off > 0; off >>= 1) sum += __shfl_xor(sum, off);
    uint32_t pk[4];
#pragma unroll
    for (int i = 0; i < 4; ++i) {
      f16 hh = (f16)e[i];
      uint32_t hb = (uint32_t)__builtin_bit_cast(uint16_t, hh);
      uint32_t nb = (uint32_t)__shfl_xor((int)hb, 1);
      pk[i] = (hb & 0xffffu) | (nb << 16);
    }
    float acc = 0.f;
#pragma unroll 4
    for (int p = 0; p < 32; ++p) {
#pragma unroll
      for (int i = 0; i < 4; ++i) {
        uint32_t pe = (uint32_t)__shfl((int)pk[i], 2 * p);
        uint32_t uv = vp_t[lane * 128 + ((i * 32 + p) ^ (lane & 31))];
        acc = fdot2f(uv, pe, acc);
      }
    }
    aout[((size_t)(b * TB + row)) * NDIM + h * DH + lane] = (f16)(acc / sum);
  }
}

// ---------------------------------------------------------------------------
// Stage 5: Out = aout @ W0t^T  (M=16384, N=1024, K=1024) fp16 MFMA, fp32 out.
// ---------------------------------------------------------------------------
__launch_bounds__(256)
__global__ void k_out(const f16* __restrict__ A, const f16* __restrict__ Bt,
                      float* __restrict__ Out) {
  __shared__ __align__(16) f16 As[128 * 32];
  __shared__ __align__(16) f16 Bs[128 * 32];
  const int tid = threadIdx.x;
  const int w = tid >> 6, lane = tid & 63;
  const int quad = lane >> 4, l15 = lane & 15;
  const int bn0 = blockIdx.x * 128, bm0 = blockIdx.y * 128;
  const int wm = (w & 1) * 64, wn = (w >> 1) * 64;
  const int srow = lane >> 2, skc = lane & 3;

  f32x4 acc[4][4];
#pragma unroll
  for (int i = 0; i < 4; ++i)
#pragma unroll
    for (int j = 0; j < 4; ++j) acc[i][j] = (f32x4){0.f, 0.f, 0.f, 0.f};

  const f16* Ag0 = A + (size_t)(bm0 + w * 32 + srow) * NDIM + skc * 8;
  const f16* Bg0 = Bt + (size_t)(bn0 + w * 32 + srow) * NDIM + skc * 8;
  f16* Al0 = As + (w * 32) * 32;
  f16* Bl0 = Bs + (w * 32) * 32;

  for (int k0 = 0; k0 < NDIM; k0 += 32) {
    glds16(Ag0 + k0, Al0);
    glds16(Ag0 + (size_t)16 * NDIM + k0, Al0 + 16 * 32);
    glds16(Bg0 + k0, Bl0);
    glds16(Bg0 + (size_t)16 * NDIM + k0, Bl0 + 16 * 32);
    __syncthreads();
    f16x8 a[4], b[4];
#pragma unroll
    for (int i = 0; i < 4; ++i) a[i] = *(const f16x8*)(As + (wm + i * 16 + l15) * 32 + quad * 8);
#pragma unroll
    for (int j = 0; j < 4; ++j) b[j] = *(const f16x8*)(Bs + (wn + j * 16 + l15) * 32 + quad * 8);
#pragma unroll
    for (int i = 0; i < 4; ++i)
#pragma unroll
      for (int j = 0; j < 4; ++j)
        acc[i][j] = __builtin_amdgcn_mfma_f32_16x16x32_f16(a[i], b[j], acc[i][j], 0, 0, 0);
    __syncthreads();
  }

#pragma unroll
  for (int i = 0; i < 4; ++i) {
    int m = bm0 + wm + i * 16 + quad * 4;
#pragma unroll
    for (int j = 0; j < 4; ++j) {
      int n = bn0 + wn + j * 16 + l15;
#pragma unroll
      for (int r = 0; r < 4; ++r) Out[(size_t)(m + r) * NDIM + n] = acc[i][j][r];
    }
  }
}

// ---------------------------------------------------------------------------
extern "C" void kernel_launch(void* const* d_in, const int* in_sizes, int n_in,
                              void* d_out, int out_size, void* d_ws, size_t ws_size,
                              hipStream_t stream) {
  const float* X    = (const float*)d_in[0];  // [4,4096,1024]
  const float* P    = (const float*)d_in[1];  // [4096,256]
  const float* Wqkv = (const float*)d_in[2];  // [1024,3072]
  const float* W0   = (const float*)d_in[3];  // [1024,1024]
  float* Out = (float*)d_out;

  char* ws = (char*)d_ws;
  const size_t MB = 1ull << 20;
  f16* Xh   = (f16*)(ws);             // 32 MB (reused as aout after k_qkv)
  f16* aout = (f16*)(ws);
  f16* qt   = (f16*)(ws + 32 * MB);   // 32 MB  [bh][d][t]
  f16* kvt  = (f16*)(ws + 64 * MB);   // 64 MB  [r][bh][d][t]
  f16* kpv  = (f16*)(ws + 128 * MB);  // 4 MB   [r][bh][kappa][d]
  f16* Wqt  = (f16*)(ws + 132 * MB);  // 6 MB   [3072][1024]
  f16* W0t  = (f16*)(ws + 138 * MB);  // 2 MB   [1024][1024]
  f16* Ptb  = (f16*)(ws + 140 * MB);  // 2 MB   [256][4096]
  // total 142 MB

  cvt_x<<<dim3(8192), 256, 0, stream>>>(X, Xh);
  cvt_t<<<dim3(48, 16), 256, 0, stream>>>(Wqkv, Wqt, 1024, 3072);
  cvt_t<<<dim3(16, 16), 256, 0, stream>>>(W0, W0t, 1024, 1024);
  cvt_t<<<dim3(4, 64), 256, 0, stream>>>(P, Ptb, 4096, 256);
  k_qkv<<<dim3(24, 128), 256, 0, stream>>>(Xh, Wqt, qt, kvt);
  k_proj<<<dim3(2, 64, 2), 256, 0, stream>>>(Ptb, kvt, kpv);
  k_attn<<<dim3(128, 64), 256, 0, stream>>>(qt, kpv, aout);
  k_out<<<dim3(8, 128), 256, 0, stream>>>(aout, W0t, Out);
}

// Round 3
// 660.795 us; speedup vs baseline: 4.5368x; 1.7653x over previous
//
#include <hip/hip_runtime.h>
#include <stdint.h>
#include <stddef.h>

#define TB    4096
#define NDIM  1024
#define NH    16
#define KPROJ 256
#define DH    64
#define NBH   64

typedef _Float16 f16;
typedef _Float16 f16x8 __attribute__((ext_vector_type(8)));
typedef float    f32x4 __attribute__((ext_vector_type(4)));

__device__ __forceinline__ void glds16(const f16* g, f16* l) {
  __builtin_amdgcn_global_load_lds((const __attribute__((address_space(1))) void*)g,
                                   (__attribute__((address_space(3))) void*)l, 16, 0, 0);
}

// ---------------------------------------------------------------------------
// fp32 -> fp16 elementwise (X)
// ---------------------------------------------------------------------------
__launch_bounds__(256)
__global__ void cvt_x(const float* __restrict__ in, f16* __restrict__ out) {
  size_t i = ((size_t)blockIdx.x * 256 + threadIdx.x) * 8;
  float4 v0 = *(const float4*)(in + i);
  float4 v1 = *(const float4*)(in + i + 4);
  union { f16 h[8]; uint4 u; } pk;
  pk.h[0] = (f16)v0.x; pk.h[1] = (f16)v0.y; pk.h[2] = (f16)v0.z; pk.h[3] = (f16)v0.w;
  pk.h[4] = (f16)v1.x; pk.h[5] = (f16)v1.y; pk.h[6] = (f16)v1.z; pk.h[7] = (f16)v1.w;
  *(uint4*)(out + i) = pk.u;
}

// ---------------------------------------------------------------------------
// fp32 [R][C] -> fp16 transposed [C][R]
// ---------------------------------------------------------------------------
__launch_bounds__(256)
__global__ void cvt_t(const float* __restrict__ in, f16* __restrict__ out, int R, int C) {
  __shared__ __align__(16) f16 s[64][72];
  const int tid = threadIdx.x;
  const int c0 = blockIdx.x * 64, r0 = blockIdx.y * 64;
#pragma unroll
  for (int it = 0; it < 4; ++it) {
    int chunk = it * 256 + tid;
    int r_l = chunk >> 4, c4 = (chunk & 15) * 4;
    float4 v = *(const float4*)(in + (size_t)(r0 + r_l) * C + c0 + c4);
    s[c4 + 0][r_l] = (f16)v.x; s[c4 + 1][r_l] = (f16)v.y;
    s[c4 + 2][r_l] = (f16)v.z; s[c4 + 3][r_l] = (f16)v.w;
  }
  __syncthreads();
#pragma unroll
  for (int it = 0; it < 2; ++it) {
    int chunk = it * 256 + tid;
    int c_l = chunk >> 3, rc = (chunk & 7) * 8;
    *(uint4*)(out + (size_t)(c0 + c_l) * R + r0 + rc) = *(const uint4*)&s[c_l][rc];
  }
}

// ---------------------------------------------------------------------------
// Stage 1: qkv = Xh @ Wt^T  (M=16384, N=3072, K=1024) fp16 MFMA, 128x128x32.
// Epilogue: einops split f = 48d+16r+h, store q/k/v TRANSPOSED [bh][d][t].
// ---------------------------------------------------------------------------
__launch_bounds__(256)
__global__ void k_qkv(const f16* __restrict__ Xh, const f16* __restrict__ Wt,
                      f16* __restrict__ qt, f16* __restrict__ kvt) {
  __shared__ __align__(16) f16 As[128 * 32];
  __shared__ __align__(16) f16 Bs[128 * 32];
  const int tid = threadIdx.x;
  const int w = tid >> 6, lane = tid & 63;
  const int quad = lane >> 4, l15 = lane & 15;
  const int bn0 = blockIdx.x * 128, bm0 = blockIdx.y * 128;
  const int wm = (w & 1) * 64, wn = (w >> 1) * 64;
  const int srow = lane >> 2, skc = lane & 3;

  f32x4 acc[4][4];
#pragma unroll
  for (int i = 0; i < 4; ++i)
#pragma unroll
    for (int j = 0; j < 4; ++j) acc[i][j] = (f32x4){0.f, 0.f, 0.f, 0.f};

  const f16* Ag0 = Xh + (size_t)(bm0 + w * 32 + srow) * NDIM + skc * 8;
  const f16* Bg0 = Wt + (size_t)(bn0 + w * 32 + srow) * NDIM + skc * 8;
  f16* Al0 = As + (w * 32) * 32;
  f16* Bl0 = Bs + (w * 32) * 32;

  for (int k0 = 0; k0 < NDIM; k0 += 32) {
    glds16(Ag0 + k0, Al0);
    glds16(Ag0 + (size_t)16 * NDIM + k0, Al0 + 16 * 32);
    glds16(Bg0 + k0, Bl0);
    glds16(Bg0 + (size_t)16 * NDIM + k0, Bl0 + 16 * 32);
    __syncthreads();
    f16x8 a[4], b[4];
#pragma unroll
    for (int i = 0; i < 4; ++i) a[i] = *(const f16x8*)(As + (wm + i * 16 + l15) * 32 + quad * 8);
#pragma unroll
    for (int j = 0; j < 4; ++j) b[j] = *(const f16x8*)(Bs + (wn + j * 16 + l15) * 32 + quad * 8);
#pragma unroll
    for (int i = 0; i < 4; ++i)
#pragma unroll
      for (int j = 0; j < 4; ++j)
        acc[i][j] = __builtin_amdgcn_mfma_f32_16x16x32_f16(a[i], b[j], acc[i][j], 0, 0, 0);
    __syncthreads();
  }

#pragma unroll
  for (int i = 0; i < 4; ++i) {
    int mrow = bm0 + wm + i * 16 + quad * 4;
    int bb = mrow >> 12, t = mrow & 4095;
#pragma unroll
    for (int j = 0; j < 4; ++j) {
      int f = bn0 + wn + j * 16 + l15;
      int d = f / 48;
      int rem = f - d * 48;
      int rr = rem >> 4, h = rem & 15;
      f16* base = (rr == 0) ? qt : kvt + (size_t)(rr - 1) * ((size_t)NBH * DH * TB);
      size_t off = ((size_t)((bb * NH + h) * DH + d)) * TB + t;
      union { f16 hh[4]; uint2 u; } pk;
#pragma unroll
      for (int r = 0; r < 4; ++r) pk.hh[r] = (f16)acc[i][j][r];
      *(uint2*)(base + off) = pk.u;
    }
  }
}

// ---------------------------------------------------------------------------
// Stage 2: kp/vp = Pt @ kvt^T per (bh, r): M=128(kappa), N=64(d), K=4096(t).
// rv==0 (k): store kp [bh][kappa][d]   (contiguous d for S B-frags)
// rv==1 (v): store vpT [bh][d][kappa]  (contiguous kappa for PV B-frags)
// ---------------------------------------------------------------------------
__launch_bounds__(256)
__global__ void k_proj(const f16* __restrict__ Pt, const f16* __restrict__ kvt,
                       f16* __restrict__ kpv) {
  __shared__ __align__(16) f16 As[128 * 32];
  __shared__ __align__(16) f16 Bs[64 * 32];
  const int tid = threadIdx.x;
  const int w = tid >> 6, lane = tid & 63;
  const int quad = lane >> 4, l15 = lane & 15;
  const int km0 = blockIdx.x * 128;
  const int bh = blockIdx.y, rv = blockIdx.z;
  const int srow = lane >> 2, skc = lane & 3;
  const f16* Bbase = kvt + (size_t)(rv * NBH + bh) * DH * TB;  // [d][t]

  f32x4 acc[2][4];
#pragma unroll
  for (int i = 0; i < 2; ++i)
#pragma unroll
    for (int j = 0; j < 4; ++j) acc[i][j] = (f32x4){0.f, 0.f, 0.f, 0.f};

  const f16* Ag0 = Pt + (size_t)(km0 + w * 32 + srow) * TB + skc * 8;
  const f16* Bg0 = Bbase + (size_t)(w * 16 + srow) * TB + skc * 8;
  f16* Al0 = As + (w * 32) * 32;
  f16* Bl0 = Bs + (w * 16) * 32;

  for (int k0 = 0; k0 < TB; k0 += 32) {
    glds16(Ag0 + k0, Al0);
    glds16(Ag0 + (size_t)16 * TB + k0, Al0 + 16 * 32);
    glds16(Bg0 + k0, Bl0);
    __syncthreads();
    f16x8 a[2], b[4];
#pragma unroll
    for (int i = 0; i < 2; ++i) a[i] = *(const f16x8*)(As + (w * 32 + i * 16 + l15) * 32 + quad * 8);
#pragma unroll
    for (int j = 0; j < 4; ++j) b[j] = *(const f16x8*)(Bs + (j * 16 + l15) * 32 + quad * 8);
#pragma unroll
    for (int i = 0; i < 2; ++i)
#pragma unroll
      for (int j = 0; j < 4; ++j)
        acc[i][j] = __builtin_amdgcn_mfma_f32_16x16x32_f16(a[i], b[j], acc[i][j], 0, 0, 0);
    __syncthreads();
  }

  if (rv == 0) {
#pragma unroll
    for (int i = 0; i < 2; ++i) {
      int kap0 = km0 + w * 32 + i * 16 + quad * 4;
#pragma unroll
      for (int j = 0; j < 4; ++j) {
        int d = j * 16 + l15;
#pragma unroll
        for (int r = 0; r < 4; ++r)
          kpv[((size_t)bh * KPROJ + kap0 + r) * DH + d] = (f16)acc[i][j][r];
      }
    }
  } else {
    f16* vpT = kpv + (size_t)NBH * KPROJ * DH;
#pragma unroll
    for (int i = 0; i < 2; ++i) {
      int kap0 = km0 + w * 32 + i * 16 + quad * 4;
#pragma unroll
      for (int j = 0; j < 4; ++j) {
        int d = j * 16 + l15;
        union { f16 hh[4]; uint2 u; } pk;
#pragma unroll
        for (int r = 0; r < 4; ++r) pk.hh[r] = (f16)acc[i][j][r];
        *(uint2*)&vpT[((size_t)bh * DH + d) * KPROJ + kap0] = pk.u;
      }
    }
  }
}

// ---------------------------------------------------------------------------
// Stage 3+4: fused MFMA attention. grid (T/64, 64 bh), 4 waves; wave owns 16
// q-rows. S = q@kp^T (16 n-tiles), softmax in C-layout regs, P via LDS
// round-trip (wave-private, padded), PV = P@vp with vpT B-frags from global.
// ---------------------------------------------------------------------------
__launch_bounds__(256)
__global__ void k_attn(const f16* __restrict__ qt, const f16* __restrict__ kpv,
                       f16* __restrict__ aout) {
  __shared__ __align__(16) f16 Ps[4][16][264];  // 33 KB, row stride 528B (2-way free)
  const int tid = threadIdx.x;
  const int w = tid >> 6, lane = tid & 63;
  const int quad = lane >> 4, l15 = lane & 15;
  const int bh = blockIdx.y;
  const int t0 = blockIdx.x * 64 + w * 16;
  const int b = bh >> 4, h = bh & 15;

  // q A-frags: A[m=l15][k=quad*8+j], k = ks*32+quad*8+j, from qt [bh][d][t]
  f16x8 aq[2];
  {
    const f16* qb = qt + (size_t)bh * DH * TB + t0 + l15;
#pragma unroll
    for (int ks = 0; ks < 2; ++ks)
#pragma unroll
      for (int j = 0; j < 8; ++j)
        aq[ks][j] = qb[(size_t)(ks * 32 + quad * 8 + j) * TB];
  }

  // S: 16 n-tiles of 16 kappa; B-frags straight from global (L2-resident)
  f32x4 sc[16];
  const f16* kpb = kpv + (size_t)bh * (KPROJ * DH);
#pragma unroll 4
  for (int nt = 0; nt < 16; ++nt) {
    f16x8 b0 = *(const f16x8*)(kpb + (size_t)(nt * 16 + l15) * DH + quad * 8);
    f16x8 b1 = *(const f16x8*)(kpb + (size_t)(nt * 16 + l15) * DH + 32 + quad * 8);
    f32x4 c = (f32x4){0.f, 0.f, 0.f, 0.f};
    c = __builtin_amdgcn_mfma_f32_16x16x32_f16(aq[0], b0, c, 0, 0, 0);
    c = __builtin_amdgcn_mfma_f32_16x16x32_f16(aq[1], b1, c, 0, 0, 0);
    sc[nt] = c;
  }

  // softmax over the 256 columns; rows live at (quad*4+r), cols nt*16+l15
  float mx[4] = {-1e30f, -1e30f, -1e30f, -1e30f};
#pragma unroll
  for (int nt = 0; nt < 16; ++nt)
#pragma unroll
    for (int r = 0; r < 4; ++r) {
      float s = sc[nt][r] * 0.125f;
      sc[nt][r] = s;
      mx[r] = fmaxf(mx[r], s);
    }
#pragma unroll
  for (int r = 0; r < 4; ++r)
#pragma unroll
    for (int off = 1; off < 16; off <<= 1) mx[r] = fmaxf(mx[r], __shfl_xor(mx[r], off));
  float sm[4] = {0.f, 0.f, 0.f, 0.f};
#pragma unroll
  for (int nt = 0; nt < 16; ++nt)
#pragma unroll
    for (int r = 0; r < 4; ++r) {
      float e = __expf(sc[nt][r] - mx[r]);
      sc[nt][r] = e;
      sm[r] += e;
    }
#pragma unroll
  for (int r = 0; r < 4; ++r)
#pragma unroll
    for (int off = 1; off < 16; off <<= 1) sm[r] += __shfl_xor(sm[r], off);

  // P -> LDS (pack lane pairs -> b32 writes, even l15 lanes only)
#pragma unroll
  for (int nt = 0; nt < 16; ++nt)
#pragma unroll
    for (int r = 0; r < 4; ++r) {
      f16 hh = (f16)sc[nt][r];
      uint32_t hb = (uint32_t)__builtin_bit_cast(uint16_t, hh);
      uint32_t nb = (uint32_t)__shfl_xor((int)hb, 1);
      if (!(lane & 1))
        *(uint32_t*)&Ps[w][quad * 4 + r][nt * 16 + l15] = (hb & 0xffffu) | (nb << 16);
    }

  // PV: M=16 t, N=64 d, K=256 kappa; A from Ps, B from vpT global
  f32x4 oc[4];
#pragma unroll
  for (int j = 0; j < 4; ++j) oc[j] = (f32x4){0.f, 0.f, 0.f, 0.f};
  const f16* vpb = kpv + (size_t)NBH * KPROJ * DH + (size_t)bh * (DH * KPROJ);
#pragma unroll 2
  for (int kk = 0; kk < 8; ++kk) {
    f16x8 pa = *(const f16x8*)&Ps[w][l15][kk * 32 + quad * 8];
#pragma unroll
    for (int nd = 0; nd < 4; ++nd) {
      f16x8 bv = *(const f16x8*)(vpb + (size_t)(nd * 16 + l15) * KPROJ + kk * 32 + quad * 8);
      oc[nd] = __builtin_amdgcn_mfma_f32_16x16x32_f16(pa, bv, oc[nd], 0, 0, 0);
    }
  }

  // epilogue: divide by row sum, store aout [b][t][h*64+d]
#pragma unroll
  for (int nd = 0; nd < 4; ++nd)
#pragma unroll
    for (int r = 0; r < 4; ++r) {
      int t = t0 + quad * 4 + r;
      aout[((size_t)(b * TB + t)) * NDIM + h * 64 + nd * 16 + l15] = (f16)(oc[nd][r] / sm[r]);
    }
}

// ---------------------------------------------------------------------------
// Stage 5: Out = aout @ W0t^T  (M=16384, N=1024, K=1024) fp16 MFMA, fp32 out.
// ---------------------------------------------------------------------------
__launch_bounds__(256)
__global__ void k_out(const f16* __restrict__ A, const f16* __restrict__ Bt,
                      float* __restrict__ Out) {
  __shared__ __align__(16) f16 As[128 * 32];
  __shared__ __align__(16) f16 Bs[128 * 32];
  const int tid = threadIdx.x;
  const int w = tid >> 6, lane = tid & 63;
  const int quad = lane >> 4, l15 = lane & 15;
  const int bn0 = blockIdx.x * 128, bm0 = blockIdx.y * 128;
  const int wm = (w & 1) * 64, wn = (w >> 1) * 64;
  const int srow = lane >> 2, skc = lane & 3;

  f32x4 acc[4][4];
#pragma unroll
  for (int i = 0; i < 4; ++i)
#pragma unroll
    for (int j = 0; j < 4; ++j) acc[i][j] = (f32x4){0.f, 0.f, 0.f, 0.f};

  const f16* Ag0 = A + (size_t)(bm0 + w * 32 + srow) * NDIM + skc * 8;
  const f16* Bg0 = Bt + (size_t)(bn0 + w * 32 + srow) * NDIM + skc * 8;
  f16* Al0 = As + (w * 32) * 32;
  f16* Bl0 = Bs + (w * 32) * 32;

  for (int k0 = 0; k0 < NDIM; k0 += 32) {
    glds16(Ag0 + k0, Al0);
    glds16(Ag0 + (size_t)16 * NDIM + k0, Al0 + 16 * 32);
    glds16(Bg0 + k0, Bl0);
    glds16(Bg0 + (size_t)16 * NDIM + k0, Bl0 + 16 * 32);
    __syncthreads();
    f16x8 a[4], b[4];
#pragma unroll
    for (int i = 0; i < 4; ++i) a[i] = *(const f16x8*)(As + (wm + i * 16 + l15) * 32 + quad * 8);
#pragma unroll
    for (int j = 0; j < 4; ++j) b[j] = *(const f16x8*)(Bs + (wn + j * 16 + l15) * 32 + quad * 8);
#pragma unroll
    for (int i = 0; i < 4; ++i)
#pragma unroll
      for (int j = 0; j < 4; ++j)
        acc[i][j] = __builtin_amdgcn_mfma_f32_16x16x32_f16(a[i], b[j], acc[i][j], 0, 0, 0);
    __syncthreads();
  }

#pragma unroll
  for (int i = 0; i < 4; ++i) {
    int m = bm0 + wm + i * 16 + quad * 4;
#pragma unroll
    for (int j = 0; j < 4; ++j) {
      int n = bn0 + wn + j * 16 + l15;
#pragma unroll
      for (int r = 0; r < 4; ++r) Out[(size_t)(m + r) * NDIM + n] = acc[i][j][r];
    }
  }
}

// ---------------------------------------------------------------------------
extern "C" void kernel_launch(void* const* d_in, const int* in_sizes, int n_in,
                              void* d_out, int out_size, void* d_ws, size_t ws_size,
                              hipStream_t stream) {
  const float* X    = (const float*)d_in[0];  // [4,4096,1024]
  const float* P    = (const float*)d_in[1];  // [4096,256]
  const float* Wqkv = (const float*)d_in[2];  // [1024,3072]
  const float* W0   = (const float*)d_in[3];  // [1024,1024]
  float* Out = (float*)d_out;

  char* ws = (char*)d_ws;
  const size_t MB = 1ull << 20;
  f16* Xh   = (f16*)(ws);             // 32 MB (reused as aout after k_qkv)
  f16* aout = (f16*)(ws);
  f16* qt   = (f16*)(ws + 32 * MB);   // 32 MB  [bh][d][t]
  f16* kvt  = (f16*)(ws + 64 * MB);   // 64 MB  [r][bh][d][t]
  f16* kpv  = (f16*)(ws + 128 * MB);  // 4 MB   kp [bh][kap][d] + vpT [bh][d][kap]
  f16* Wqt  = (f16*)(ws + 132 * MB);  // 6 MB   [3072][1024]
  f16* W0t  = (f16*)(ws + 138 * MB);  // 2 MB   [1024][1024]
  f16* Ptb  = (f16*)(ws + 140 * MB);  // 2 MB   [256][4096]

  cvt_x<<<dim3(8192), 256, 0, stream>>>(X, Xh);
  cvt_t<<<dim3(48, 16), 256, 0, stream>>>(Wqkv, Wqt, 1024, 3072);
  cvt_t<<<dim3(16, 16), 256, 0, stream>>>(W0, W0t, 1024, 1024);
  cvt_t<<<dim3(4, 64), 256, 0, stream>>>(P, Ptb, 4096, 256);
  k_qkv<<<dim3(24, 128), 256, 0, stream>>>(Xh, Wqt, qt, kvt);
  k_proj<<<dim3(2, 64, 2), 256, 0, stream>>>(Ptb, kvt, kpv);
  k_attn<<<dim3(64, 64), 256, 0, stream>>>(qt, kpv, aout);
  k_out<<<dim3(8, 128), 256, 0, stream>>>(aout, W0t, Out);
}